// Round 1
// baseline (472.243 us; speedup 1.0000x reference)
//
#include <hip/hip_runtime.h>

// NaiveCustomLSTM: V block-diagonal (20 blocks of 32), U (nearly) diagonal.
// => 2560 independent 32-wide LSTMs (128 batch x 20 blocks), 512 steps.
// One wave per unit, one wave per workgroup (grid=2560 -> 10 waves/CU).
// Lanes 0-31: gates i,f for n=lane; lanes 32-63: gates g,o for n=lane-32.
//
// R8 change: h-broadcast via 32x v_readlane -> SGPRs (uniform results live in
// the scalar file), replacing the LDS ds_write+8x ds_read_b128 round trip.
// Rationale from R7 counters: VGPR_Count stayed 72 despite launch_bounds(64,3)
// -- hp[16] (32 VGPRs) + wA/wB (64) + xa/xb (16) exceeded the allocator's
// pressure target, so it re-materialized the V-weight loads INSIDE the
// 512-step loop (~32 L1/L2 reloads + waits per step). Moving broadcast-h to
// SGPRs frees those 32 VGPRs AND removes ~120+ cyc of LDS latency from the
// per-step serial chain. Weight/x loads are pinned with empty-asm defs so the
// remat heuristic cannot sink them back into the loop. v_fma_f32 with one
// SGPR source is legal (1 sgpr read/instr). pk_fma dropped: SGPR pairs won't
// allocate contiguously, and 32 pk + 32 movs == 64 scalar fma in issue slots.
//
// Sigmoid/tanh exp2 scales pre-folded per-lane into weights so the
// accumulator IS the exp2 arg. Only raw x (lane-uniform in n) is broadcast
// via readlane; per-lane weights applied after broadcast.

#define TT 512
#define HN 640
#define BN 128

__device__ __forceinline__ float rl(float v, int s) {
  return __int_as_float(__builtin_amdgcn_readlane(__float_as_int(v), s));
}

__global__ __launch_bounds__(64, 3) void lstm_kernel(
    const float* __restrict__ x,
    const float* __restrict__ Ui, const float* __restrict__ Vi, const float* __restrict__ bi,
    const float* __restrict__ Uf, const float* __restrict__ Vf, const float* __restrict__ bf,
    const float* __restrict__ Uc, const float* __restrict__ Vc, const float* __restrict__ bc,
    const float* __restrict__ Uo, const float* __restrict__ Vo, const float* __restrict__ bo,
    float* __restrict__ out) {
  const int unit = blockIdx.x;   // 0..2559
  const int lane = threadIdx.x;  // 0..63
  const int j = unit >> 7;       // hidden block 0..19
  const int b = unit & 127;      // batch
  const int gp = lane >> 5;      // 0: gates i,f ; 1: gates g,o
  const int n = lane & 31;
  const int col = j * 32 + n;

  const float* UG1 = gp ? Uc : Ui;
  const float* UG2 = gp ? Uo : Uf;
  const float* VG1 = gp ? Vc : Vi;
  const float* VG2 = gp ? Vo : Vf;
  const float* bG1 = gp ? bc : bi;
  const float* bG2 = gp ? bo : bf;

  const float LOG2E = 1.44269504088896340736f;
  // gate1: lo = sigmoid(i) (scale -log2e); hi = tanh(g) (scale -2log2e)
  // gate2: sigmoid (f / o) for both halves.
  const float B1 = gp ? (-2.f * LOG2E) : -LOG2E;
  const float B2 = -LOG2E;
  const float Ac1 = gp ? 2.f : 1.f;
  const float Cc1 = gp ? -1.f : 0.f;

  // Effective input weights for this block (from U mask structure).
  float w11 = 0.f, w21 = 0.f, w12 = 0.f, w22 = 0.f;
  int f1 = 0, f2i = 0;
  if (j < 16) {
    f1 = f2i = j;
    w11 = UG1[j * HN + col];
    w12 = UG2[j * HN + col];
    if (j == 0) {
      w11 += UG1[16 * HN + col]; w12 += UG2[16 * HN + col];
      w21  = UG1[17 * HN + col]; w22  = UG2[17 * HN + col];
      f2i = 1;
    } else if (j == 2) {
      w11 += UG1[18 * HN + col]; w12 += UG2[18 * HN + col];
      w21  = UG1[19 * HN + col]; w22  = UG2[19 * HN + col];
      f2i = 3;
    }
  }
  // Pre-scale per-lane input weights/bias by the exp2 factor (stays per-lane).
  const float ws11 = B1 * w11, ws21 = B1 * w21, bs1 = B1 * bG1[col];
  const float ws12 = B2 * w12, ws22 = B2 * w22, bs2 = B2 * bG2[col];

  // Recurrent weight columns, pre-scaled: wA[k] = B1*V1[k,col], wB[k] = B2*V2[k,col].
  float wA[32], wB[32];
#pragma unroll
  for (int k = 0; k < 32; ++k) {
    wA[k] = B1 * VG1[(j * 32 + k) * HN + col];
    wB[k] = B2 * VG2[(j * 32 + k) * HN + col];
  }
  // Pin the weights as VGPR-resident (opaque defs: no remat/sinking into loop).
#pragma unroll
  for (int k = 0; k < 32; ++k) {
    asm volatile("" : "+v"(wA[k]), "+v"(wB[k]));
  }

  // Stage RAW input sequence in registers (lane-uniform in n: only t varies).
  // Lane holds t = i*64+lane.
  float xa[8], xb[8];
#pragma unroll
  for (int i = 0; i < 8; ++i) {
    const int t = i * 64 + lane;
    xa[i] = x[(b * TT + t) * 16 + f1];
    xb[i] = x[(b * TT + t) * 16 + f2i];
  }
#pragma unroll
  for (int i = 0; i < 8; ++i) {
    asm volatile("" : "+v"(xa[i]), "+v"(xb[i]));
  }

  float h = 0.f, c = 0.f;  // valid in lanes 0-31; upper half carries junk
  int ob = b * TT * HN + col;
#pragma unroll
  for (int i = 0; i < 8; ++i) {
    const float xc1 = xa[i];
    const float xc2 = xb[i];
    for (int s = 0; s < 64; ++s) {
      const float x1 = rl(xc1, s);  // raw x -- safe to broadcast (uniform in n)
      const float x2 = rl(xc2, s);
      // Per-lane scaled x-contribution (weights applied AFTER broadcast).
      const float sx1 = fmaf(x2, ws21, fmaf(x1, ws11, bs1));
      const float sx2 = fmaf(x2, ws22, fmaf(x1, ws12, bs2));
      // Broadcast h via readlane: 32 uniform values -> scalar regs. Lanes
      // 0-31 hold valid h; readlane ignores exec and only touches 0..31.
      float hv[32];
#pragma unroll
      for (int k = 0; k < 32; ++k) hv[k] = rl(h, k);
      // 4 interleaved scalar-fma chains (16 deep each); one SGPR src per fma.
      float aA0 = sx1, aA1 = 0.f, aB0 = sx2, aB1 = 0.f;
#pragma unroll
      for (int k = 0; k < 32; k += 2) {
        aA0 = fmaf(wA[k],     hv[k],     aA0);
        aB0 = fmaf(wB[k],     hv[k],     aB0);
        aA1 = fmaf(wA[k + 1], hv[k + 1], aA1);
        aB1 = fmaf(wB[k + 1], hv[k + 1], aB1);
      }
      const float a1 = aA0 + aA1;  // = B1 * gate1 preactivation
      const float a2 = aB0 + aB1;  // = B2 * gate2 preactivation
      const float e1 = __builtin_amdgcn_exp2f(a1);
      const float e2 = __builtin_amdgcn_exp2f(a2);
      // lo: g1=sig(i), g2=sig(f); hi: g1=tanh(g), g2=sig(o)
      const float g1 = fmaf(Ac1, __builtin_amdgcn_rcpf(1.f + e1), Cc1);
      const float g2 = __builtin_amdgcn_rcpf(1.f + e2);
      const float p1 = __shfl_xor(g1, 32);  // lo gets tanh(g); hi gets sig(i)
      const float p2 = __shfl_xor(g2, 32);  // lo gets sig(o);  hi gets sig(f)
      c = fmaf(g2, c, g1 * p1);             // lo: c = sig(f)*c + sig(i)*tanh(g)
      const float tc = fmaf(
          2.f,
          __builtin_amdgcn_rcpf(1.f + __builtin_amdgcn_exp2f(-2.f * LOG2E * c)),
          -1.f);
      h = p2 * tc;                          // lo: h = sig(o)*tanh(c)
      if (lane < 32) out[ob] = h;
      ob += HN;
    }
  }
  if (lane < 32) {
    out[BN * TT * HN + b * HN + col] = h;             // h_t
    out[BN * TT * HN + BN * HN + b * HN + col] = c;   // c_t
  }
}

extern "C" void kernel_launch(void* const* d_in, const int* in_sizes, int n_in,
                              void* d_out, int out_size, void* d_ws, size_t ws_size,
                              hipStream_t stream) {
  (void)in_sizes; (void)n_in; (void)d_ws; (void)ws_size; (void)out_size;
  const float* x  = (const float*)d_in[0];
  const float* Ui = (const float*)d_in[1];
  const float* Vi = (const float*)d_in[2];
  const float* bi = (const float*)d_in[3];
  const float* Uf = (const float*)d_in[4];
  const float* Vf = (const float*)d_in[5];
  const float* bf = (const float*)d_in[6];
  const float* Uc = (const float*)d_in[7];
  const float* Vc = (const float*)d_in[8];
  const float* bc = (const float*)d_in[9];
  const float* Uo = (const float*)d_in[10];
  const float* Vo = (const float*)d_in[11];
  const float* bo = (const float*)d_in[12];
  float* out = (float*)d_out;

  dim3 grid(2560);  // one wave per workgroup -> ~10 waves/CU, balanced
  dim3 block(64);
  hipLaunchKernelGGL(lstm_kernel, grid, block, 0, stream,
                     x, Ui, Vi, bi, Uf, Vf, bf, Uc, Vc, bc, Uo, Vo, bo, out);
}

// Round 2
// 385.005 us; speedup vs baseline: 1.2266x; 1.2266x over previous
//
#include <hip/hip_runtime.h>

// NaiveCustomLSTM: V block-diagonal (20 blocks of 32), U (nearly) diagonal.
// => 2560 independent 32-wide LSTMs (128 batch x 20 blocks), 512 steps.
// One wave per unit, one wave per workgroup (grid=2560 -> 2.5 waves/SIMD).
// Lanes 0-31: gates i,f for n=lane; lanes 32-63: gates g,o for n=lane-32.
//
// R9 change: __attribute__((amdgpu_waves_per_eu(2,4))) replaces
// __launch_bounds__(64,3). Evidence from R7/R8: launch_bounds' 2nd arg only
// sets the register CAP (min waves/EU); the GCN scheduler still TARGETS the
// hardware-max 8 waves/EU (<=64 VGPRs) because nothing else bounds occupancy.
// R7: it rematerialized the 64 V-weight loads into the 512-step loop
// (VGPR=72). R8: asm pins blocked remat, so it spilled the pinned weights
// (VGPR=60) and paid per-use moves in-loop (+340 cyc/SIMD-step, 272->344us).
// max-waves=4 sets the pressure target to 128 VGPRs -- reachable occupancy is
// only 2.5 waves/SIMD anyway (2560 waves / 1024 SIMDs), so nothing is lost.
// VGPR<=128 keeps the 4-waves/SIMD HW step -> all waves co-resident.
// To fit 128: xa/xb staging (16 regs) dropped; x reloaded per 64-step block
// (x is 4MB, L2/L3-resident, 20x reuse -> ~200cyc per 64 steps, negligible).
//
// Inner structure = R7 (best measured): h broadcast via LDS ds_write_b32 +
// 8x same-address ds_read_b128 (conflict-free broadcast); 32x v_pk_fma_f32
// (64 MACs/step in 32 issue slots). Sigmoid/tanh exp2 scales pre-folded
// per-lane into weights so the accumulator IS the exp2 arg. Only raw x
// (lane-uniform in n) is broadcast via readlane; per-lane weights applied
// after broadcast. Weights pinned with opaque asm defs (no remat/sink).

#define TT 512
#define HN 640
#define BN 128

typedef float f2 __attribute__((ext_vector_type(2)));

__device__ __forceinline__ float rl(float v, int s) {
  return __int_as_float(__builtin_amdgcn_readlane(__float_as_int(v), s));
}

__global__ __attribute__((amdgpu_flat_work_group_size(64, 64),
                          amdgpu_waves_per_eu(2, 4)))
void lstm_kernel(
    const float* __restrict__ x,
    const float* __restrict__ Ui, const float* __restrict__ Vi, const float* __restrict__ bi,
    const float* __restrict__ Uf, const float* __restrict__ Vf, const float* __restrict__ bf,
    const float* __restrict__ Uc, const float* __restrict__ Vc, const float* __restrict__ bc,
    const float* __restrict__ Uo, const float* __restrict__ Vo, const float* __restrict__ bo,
    float* __restrict__ out) {
  __shared__ __align__(16) float hsh[64];  // [0..31] valid h, [32..63] junk sink

  const int unit = blockIdx.x;   // 0..2559
  const int lane = threadIdx.x;  // 0..63
  const int j = unit >> 7;       // hidden block 0..19
  const int b = unit & 127;      // batch
  const int gp = lane >> 5;      // 0: gates i,f ; 1: gates g,o
  const int n = lane & 31;
  const int col = j * 32 + n;

  const float* UG1 = gp ? Uc : Ui;
  const float* UG2 = gp ? Uo : Uf;
  const float* VG1 = gp ? Vc : Vi;
  const float* VG2 = gp ? Vo : Vf;
  const float* bG1 = gp ? bc : bi;
  const float* bG2 = gp ? bo : bf;

  const float LOG2E = 1.44269504088896340736f;
  // gate1: lo = sigmoid(i) (scale -log2e); hi = tanh(g) (scale -2log2e)
  // gate2: sigmoid (f / o) for both halves.
  const float B1 = gp ? (-2.f * LOG2E) : -LOG2E;
  const float B2 = -LOG2E;
  const float Ac1 = gp ? 2.f : 1.f;
  const float Cc1 = gp ? -1.f : 0.f;

  // Effective input weights for this block (from U mask structure).
  float w11 = 0.f, w21 = 0.f, w12 = 0.f, w22 = 0.f;
  int f1 = 0, f2i = 0;
  if (j < 16) {
    f1 = f2i = j;
    w11 = UG1[j * HN + col];
    w12 = UG2[j * HN + col];
    if (j == 0) {
      w11 += UG1[16 * HN + col]; w12 += UG2[16 * HN + col];
      w21  = UG1[17 * HN + col]; w22  = UG2[17 * HN + col];
      f2i = 1;
    } else if (j == 2) {
      w11 += UG1[18 * HN + col]; w12 += UG2[18 * HN + col];
      w21  = UG1[19 * HN + col]; w22  = UG2[19 * HN + col];
      f2i = 3;
    }
  }
  // Pre-scale per-lane input weights/bias by the exp2 factor (stays per-lane).
  const float ws11 = B1 * w11, ws21 = B1 * w21, bs1 = B1 * bG1[col];
  const float ws12 = B2 * w12, ws22 = B2 * w22, bs2 = B2 * bG2[col];

  // Recurrent weight columns, pre-scaled, paired over k:
  // wA[kp] = {B1*V1[2kp,col], B1*V1[2kp+1,col]}, wB likewise with B2*V2.
  f2 wA[16], wB[16];
#pragma unroll
  for (int kp = 0; kp < 16; ++kp) {
    wA[kp].x = B1 * VG1[(j * 32 + 2 * kp) * HN + col];
    wA[kp].y = B1 * VG1[(j * 32 + 2 * kp + 1) * HN + col];
    wB[kp].x = B2 * VG2[(j * 32 + 2 * kp) * HN + col];
    wB[kp].y = B2 * VG2[(j * 32 + 2 * kp + 1) * HN + col];
  }
  // Pin the weights as VGPR-resident (opaque defs: no remat/sinking into loop).
#pragma unroll
  for (int kp = 0; kp < 16; ++kp) {
    asm volatile("" : "+v"(wA[kp]), "+v"(wB[kp]));
  }

  float h = 0.f, c = 0.f;  // valid in lanes 0-31; upper half carries junk
  int ob = b * TT * HN + col;
#pragma unroll 1
  for (int i = 0; i < 8; ++i) {
    // Load this 64-step block's raw x (lane-uniform in n: only t varies).
    // Lane holds t = i*64+lane. x is 4MB -> L2/L3-resident, 20x block reuse.
    const int t = i * 64 + lane;
    float xc1 = x[(b * TT + t) * 16 + f1];
    float xc2 = x[(b * TT + t) * 16 + f2i];
    asm volatile("" : "+v"(xc1), "+v"(xc2));
    for (int s = 0; s < 64; ++s) {
      const float x1 = rl(xc1, s);  // raw x -- safe to broadcast
      const float x2 = rl(xc2, s);
      // Per-lane scaled x-contribution (weights applied AFTER broadcast).
      const float sx1 = fmaf(x2, ws21, fmaf(x1, ws11, bs1));
      const float sx2 = fmaf(x2, ws22, fmaf(x1, ws12, bs2));
      // Broadcast h through LDS. All lanes store (no divergence); only
      // [0..31] is meaningful. Same-wave DS ops execute in order.
      hsh[lane] = h;
      __builtin_amdgcn_wave_barrier();
      f2 hp[16];
      __builtin_memcpy(hp, hsh, 128);  // 8x broadcast ds_read_b128, in place
      __builtin_amdgcn_wave_barrier();
      f2 aA = {sx1, 0.f}, aB = {sx2, 0.f};
#pragma unroll
      for (int kp = 0; kp < 16; ++kp) {
        aA = __builtin_elementwise_fma(wA[kp], hp[kp], aA);  // v_pk_fma_f32
        aB = __builtin_elementwise_fma(wB[kp], hp[kp], aB);
      }
      const float a1 = aA.x + aA.y;  // = B1 * gate1 preactivation
      const float a2 = aB.x + aB.y;  // = B2 * gate2 preactivation
      const float e1 = __builtin_amdgcn_exp2f(a1);
      const float e2 = __builtin_amdgcn_exp2f(a2);
      // lo: g1=sig(i), g2=sig(f); hi: g1=tanh(g), g2=sig(o)
      const float g1 = fmaf(Ac1, __builtin_amdgcn_rcpf(1.f + e1), Cc1);
      const float g2 = __builtin_amdgcn_rcpf(1.f + e2);
      const float p1 = __shfl_xor(g1, 32);  // lo gets tanh(g); hi gets sig(i)
      const float p2 = __shfl_xor(g2, 32);  // lo gets sig(o);  hi gets sig(f)
      c = fmaf(g2, c, g1 * p1);             // lo: c = sig(f)*c + sig(i)*tanh(g)
      const float tc = fmaf(
          2.f,
          __builtin_amdgcn_rcpf(1.f + __builtin_amdgcn_exp2f(-2.f * LOG2E * c)),
          -1.f);
      h = p2 * tc;                          // lo: h = sig(o)*tanh(c)
      if (lane < 32) out[ob] = h;
      ob += HN;
    }
  }
  if (lane < 32) {
    out[BN * TT * HN + b * HN + col] = h;             // h_t
    out[BN * TT * HN + BN * HN + b * HN + col] = c;   // c_t
  }
}

extern "C" void kernel_launch(void* const* d_in, const int* in_sizes, int n_in,
                              void* d_out, int out_size, void* d_ws, size_t ws_size,
                              hipStream_t stream) {
  (void)in_sizes; (void)n_in; (void)d_ws; (void)ws_size; (void)out_size;
  const float* x  = (const float*)d_in[0];
  const float* Ui = (const float*)d_in[1];
  const float* Vi = (const float*)d_in[2];
  const float* bi = (const float*)d_in[3];
  const float* Uf = (const float*)d_in[4];
  const float* Vf = (const float*)d_in[5];
  const float* bf = (const float*)d_in[6];
  const float* Uc = (const float*)d_in[7];
  const float* Vc = (const float*)d_in[8];
  const float* bc = (const float*)d_in[9];
  const float* Uo = (const float*)d_in[10];
  const float* Vo = (const float*)d_in[11];
  const float* bo = (const float*)d_in[12];
  float* out = (float*)d_out;

  dim3 grid(2560);  // one wave per workgroup -> 2.5 waves/SIMD, balanced
  dim3 block(64);
  hipLaunchKernelGGL(lstm_kernel, grid, block, 0, stream,
                     x, Ui, Vi, bi, Uf, Vf, bf, Uc, Vc, bc, Uo, Vo, bo, out);
}